// Round 2
// baseline (27915.039 us; speedup 1.0000x reference)
//
#include <hip/hip_runtime.h>
#include <math.h>

#define N_NODES 10000
#define N_EDGES 320000
#define GRID 250
#define BLOCK 512
#define WPB 8            // waves per block
#define NPW 5            // nodes per wave
#define NPB 40           // nodes per block (WPB*NPW)
#define ECAP 2048        // LDS edge cache capacity per block (mean 1280, ~+21 sigma)

// ---------------- device-scope atomic helpers (cross-XCD safe) ----------------
__device__ __forceinline__ float ald(const float* p) {
    return __hip_atomic_load((float*)p, __ATOMIC_RELAXED, __HIP_MEMORY_SCOPE_AGENT);
}
__device__ __forceinline__ void ast(float* p, float v) {
    __hip_atomic_store(p, v, __ATOMIC_RELAXED, __HIP_MEMORY_SCOPE_AGENT);
}

// ---------------- grid barrier (all 250 blocks co-resident: 1 block/CU) -------
__device__ __forceinline__ void gbar(int* bar) {
    __syncthreads();
    __threadfence();
    if (threadIdx.x == 0) {
        int* ctr = bar;
        int* gen = bar + 64;
        int g = __hip_atomic_load(gen, __ATOMIC_RELAXED, __HIP_MEMORY_SCOPE_AGENT);
        int a = __hip_atomic_fetch_add(ctr, 1, __ATOMIC_ACQ_REL, __HIP_MEMORY_SCOPE_AGENT);
        if (a == GRID - 1) {
            __hip_atomic_store(ctr, 0, __ATOMIC_RELAXED, __HIP_MEMORY_SCOPE_AGENT);
            __hip_atomic_fetch_add(gen, 1, __ATOMIC_ACQ_REL, __HIP_MEMORY_SCOPE_AGENT);
        } else {
            while (__hip_atomic_load(gen, __ATOMIC_ACQUIRE, __HIP_MEMORY_SCOPE_AGENT) == g)
                __builtin_amdgcn_s_sleep(2);
        }
    }
    __syncthreads();
    __threadfence();
}

// ---------------- setup kernels ----------------
__global__ void k_init(float* deg, int* cnt, int* fill, int* bar, int n) {
    int i = blockIdx.x * blockDim.x + threadIdx.x;
    if (i < n) { deg[i] = 0.f; cnt[i] = 0; fill[i] = 0; }
    if (i < 128) bar[i] = 0;
}

__global__ void k_deg(const int* __restrict__ ei, const float* __restrict__ w,
                      float* deg, int E) {
    int e = blockIdx.x * blockDim.x + threadIdx.x;
    if (e < E) atomicAdd(&deg[ei[e]], w[e]);
}

__global__ void k_dis(float* deg, int n) {
    int i = blockIdx.x * blockDim.x + threadIdx.x;
    if (i < n) {
        float d = deg[i];
        deg[i] = (d > 0.f) ? (float)(1.0 / sqrt((double)d)) : 0.f;
    }
}

__global__ void k_norm(const int* __restrict__ ei, const float* __restrict__ w,
                       const float* __restrict__ dis, float* __restrict__ normw,
                       int* cnt, int E) {
    int e = blockIdx.x * blockDim.x + threadIdx.x;
    if (e < E) {
        int s = ei[e], d = ei[E + e];
        normw[e] = -dis[s] * w[e] * dis[d];
        atomicAdd(&cnt[d], 1);
    }
}

__global__ void k_scan(const int* __restrict__ cnt, int* __restrict__ rowptr, int n) {
    __shared__ int part[1024];
    const int PER = 10;
    int t = threadIdx.x;
    int base = t * PER;
    int local[PER];
    int s = 0;
    for (int j = 0; j < PER; j++) {
        int idx = base + j;
        int v = (idx < n) ? cnt[idx] : 0;
        local[j] = v; s += v;
    }
    part[t] = s;
    __syncthreads();
    for (int off = 1; off < 1024; off <<= 1) {
        int v = part[t];
        int u = (t >= off) ? part[t - off] : 0;
        __syncthreads();
        part[t] = v + u;
        __syncthreads();
    }
    int excl = (t > 0) ? part[t - 1] : 0;
    for (int j = 0; j < PER; j++) {
        int idx = base + j;
        if (idx < n) rowptr[idx] = excl;
        excl += local[j];
    }
    if (t == 1023) rowptr[n] = part[1023];
}

__global__ void k_fill(const int* __restrict__ ei, const float* __restrict__ normw,
                       const int* __restrict__ rowptr, int* fill,
                       int* __restrict__ csr_src, float* __restrict__ csr_norm, int E) {
    int e = blockIdx.x * blockDim.x + threadIdx.x;
    if (e < E) {
        int d = ei[E + e];
        int pos = atomicAdd(&fill[d], 1);
        int idx = rowptr[d] + pos;
        csr_src[idx] = ei[e];
        csr_norm[idx] = normw[e];
    }
}

// ---------------- gathers ----------------
// wide: lane = channel c (CI in {60,64}), serial over edges, unroll-16 for ILP
template <bool L>
__device__ __forceinline__ float gather_wide(
    const float* __restrict__ gs, int st, int lane, int rb, int dg,
    const int* ls_src, const float* ls_nw,
    const int* __restrict__ g_src, const float* __restrict__ g_nw)
{
    float agg = 0.f;
    int e = 0;
    for (; e + 16 <= dg; e += 16) {
        float v[16], wv[16];
#pragma unroll
        for (int u = 0; u < 16; u++) {
            int idx = rb + e + u;
            int s = L ? ls_src[idx] : g_src[idx];
            wv[u]  = L ? ls_nw[idx]  : g_nw[idx];
            v[u] = ald(&gs[s * st + lane]);
        }
#pragma unroll
        for (int u = 0; u < 16; u++) agg = fmaf(wv[u], v[u], agg);
    }
    for (; e + 4 <= dg; e += 4) {
        float v[4], wv[4];
#pragma unroll
        for (int u = 0; u < 4; u++) {
            int idx = rb + e + u;
            int s = L ? ls_src[idx] : g_src[idx];
            wv[u]  = L ? ls_nw[idx]  : g_nw[idx];
            v[u] = ald(&gs[s * st + lane]);
        }
#pragma unroll
        for (int u = 0; u < 4; u++) agg = fmaf(wv[u], v[u], agg);
    }
    for (; e < dg; e++) {
        int idx = rb + e;
        int s = L ? ls_src[idx] : g_src[idx];
        float w = L ? ls_nw[idx] : g_nw[idx];
        agg = fmaf(w, ald(&gs[s * st + lane]), agg);
    }
    return agg;
}

// narrow (CI=4): lane = eo*4 + c, 16 edges in parallel, butterfly reduce over eo
template <bool L>
__device__ __forceinline__ float gather4(
    const float* __restrict__ gs, int lc, int eo, int rb, int dg,
    const int* ls_src, const float* ls_nw,
    const int* __restrict__ g_src, const float* __restrict__ g_nw)
{
    float agg = 0.f;
    for (int e = eo; e < dg; e += 16) {
        int idx = rb + e;
        int s = L ? ls_src[idx] : g_src[idx];
        float w = L ? ls_nw[idx] : g_nw[idx];
        agg = fmaf(w, ald(&gs[s * 4 + lc]), agg);
    }
    agg += __shfl_xor(agg, 4);
    agg += __shfl_xor(agg, 8);
    agg += __shfl_xor(agg, 16);
    agg += __shfl_xor(agg, 32);
    return agg;  // replicated across all 64 lanes, per channel c = lane&3
}

// ---------------- dense: acc[o] += sum_c t2[c] * W[c][o] ----------------
template <int CI, int CO>
__device__ __forceinline__ void dense_step(float (&acc)[NPW], const float (&t2v)[NPW],
                                           const float* lsW, int lane)
{
#pragma unroll
    for (int c = 0; c < CI; c++) {
        float wv = lsW[c * CO + lane];   // lane>=CO reads padded LDS, result discarded
#pragma unroll
        for (int j = 0; j < NPW; j++)
            acc[j] = fmaf(__shfl(t2v[j], c), wv, acc[j]);
    }
}

__device__ __forceinline__ void stage_w(const float* __restrict__ Wg, float* lsW, int cnt) {
    for (int i = threadIdx.x; i < cnt; i += BLOCK) lsW[i] = Wg[i];
}

// ---------------- one ChebConv layer inside the persistent kernel ----------------
// t1r in: own h (lane=channel map, zeros beyond CI); out: own activated output
// (lane=out-channel map, zeros beyond CO).
template <int CI, int CO, int K, int ACT, bool PUB>
__device__ void run_layer(
    float (&t1r)[NPW],
    const float* __restrict__ Wg, const float* __restrict__ bg,
    const float* __restrict__ hprev, int hst,
    float* tb0, float* tb1, int tst,
    float* __restrict__ hout,
    const int (&nodes)[NPW], const int (&rbj)[NPW], const int (&dgj)[NPW],
    bool use_lds, const int* ls_src, const float* ls_nw,
    const int* __restrict__ g_src, const float* __restrict__ g_nw,
    float* lsW, int* bar, int lane)
{
    float t0r[NPW], acc[NPW];
    // ---- k = 0: acc = b + h @ W0 ----
    __syncthreads();                       // lsW free (prev users done)
    stage_w(Wg, lsW, CI * CO);
    float bv = (bg != nullptr && lane < CO) ? bg[lane] : 0.f;
    __syncthreads();                       // lsW staged
#pragma unroll
    for (int j = 0; j < NPW; j++) { acc[j] = bv; t0r[j] = t1r[j]; }
    dense_step<CI, CO>(acc, t1r, lsW, lane);

    float* tb[2] = {tb0, tb1};
    int cur = 1;
    int lc = lane & 3, eo = lane >> 2;     // for CI==4 mapping

#pragma unroll 1
    for (int k = 1; k < K; k++) {
        __syncthreads();                   // prev dense done reading lsW
        stage_w(Wg + k * CI * CO, lsW, CI * CO);
        const float* gs = (k == 1) ? hprev : tb[cur];
        int gst = (k == 1) ? hst : tst;
        float t2v[NPW];
#pragma unroll
        for (int j = 0; j < NPW; j++) {
            float agg;
            if (CI == 4) {
                agg = use_lds
                    ? gather4<true >(gs, lc, eo, rbj[j], dgj[j], ls_src, ls_nw, g_src, g_nw)
                    : gather4<false>(gs, lc, eo, rbj[j], dgj[j], ls_src, ls_nw, g_src, g_nw);
            } else {
                agg = use_lds
                    ? gather_wide<true >(gs, gst, lane, rbj[j], dgj[j], ls_src, ls_nw, g_src, g_nw)
                    : gather_wide<false>(gs, gst, lane, rbj[j], dgj[j], ls_src, ls_nw, g_src, g_nw);
            }
            float t2 = (k == 1) ? agg : fmaf(2.f, agg, -t0r[j]);
            if (CI != 4 && lane >= CI) t2 = 0.f;
            t2v[j] = t2;
        }
        __syncthreads();                   // lsW staged
        dense_step<CI, CO>(acc, t2v, lsW, lane);
#pragma unroll
        for (int j = 0; j < NPW; j++) { t0r[j] = t1r[j]; t1r[j] = t2v[j]; }
        if (k < K - 1) {
            float* gd = tb[cur ^ 1];
#pragma unroll
            for (int j = 0; j < NPW; j++) {
                if (CI == 4) {
                    if (lane < 4) ast(&gd[nodes[j] * 4 + lane], t2v[j]);
                } else {
                    ast(&gd[nodes[j] * tst + lane], t2v[j]);
                }
            }
            cur ^= 1;
            gbar(bar);
        }
    }
    // ---- epilogue: activation, keep own output in regs, publish if needed ----
#pragma unroll
    for (int j = 0; j < NPW; j++) {
        float a = acc[j];
        float h = (ACT == 1) ? a / (1.f + expf(-a)) : a;
        if (lane >= CO) h = 0.f;
        t1r[j] = h;
    }
    if (PUB) {
#pragma unroll
        for (int j = 0; j < NPW; j++) ast(&hout[nodes[j] * 64 + lane], t1r[j]);
        gbar(bar);
    }
}

// ---------------- persistent kernel: all 4 layers, 257 grid barriers ----------------
__global__ __launch_bounds__(BLOCK, 2) void persistent(
    const float* __restrict__ x,
    const int* __restrict__ rowptr, const int* __restrict__ csr_src,
    const float* __restrict__ csr_norm,
    const float* __restrict__ W1, const float* __restrict__ b1,
    const float* __restrict__ W2, const float* __restrict__ b2,
    const float* __restrict__ W3, const float* __restrict__ b3,
    const float* __restrict__ W4,
    float* t4a, float* t4b, float* tba, float* tbb,
    float* h1, float* h2, float* out, int* bar)
{
    __shared__ int   ls_src[ECAP];
    __shared__ float ls_nw[ECAP];
    __shared__ float lsW[4096];

    int tid = threadIdx.x;
    int w = tid >> 6, lane = tid & 63;

    // block's edge range -> LDS (once, reused for all 257 steps)
    int nb0 = blockIdx.x * NPB;
    int eb = rowptr[nb0];
    int ee = rowptr[nb0 + NPB];
    int ecnt = ee - eb;
    bool use_lds = (ecnt <= ECAP);
    if (use_lds) {
        for (int i = tid; i < ecnt; i += BLOCK) {
            ls_src[i] = csr_src[eb + i];
            ls_nw[i]  = csr_norm[eb + i];
        }
    }

    // per-wave node assignment (exact: 250*40 = 10000)
    int nodes[NPW], rbj[NPW], dgj[NPW];
    int node0 = nb0 + w * NPW;
#pragma unroll
    for (int j = 0; j < NPW; j++) {
        nodes[j] = node0 + j;
        int r0 = rowptr[nodes[j]], r1 = rowptr[nodes[j] + 1];
        dgj[j] = r1 - r0;
        rbj[j] = use_lds ? (r0 - eb) : r0;
    }
    __syncthreads();

    // own input features (lane = c&3 map, replicated across lane groups)
    float t1r[NPW];
#pragma unroll
    for (int j = 0; j < NPW; j++) t1r[j] = x[nodes[j] * 4 + (lane & 3)];

    // Layer 1: K=120, 4->64, silu
    run_layer<4, 64, 120, 1, true>(t1r, W1, b1, x, 4, t4a, t4b, 4, h1,
                                   nodes, rbj, dgj, use_lds, ls_src, ls_nw,
                                   csr_src, csr_norm, lsW, bar, lane);
    // Layer 2: K=120, 64->60, silu
    run_layer<64, 60, 120, 1, true>(t1r, W2, b2, h1, 64, tba, tbb, 64, h2,
                                    nodes, rbj, dgj, use_lds, ls_src, ls_nw,
                                    csr_src, csr_norm, lsW, bar, lane);
    // Layer 3: K=20, 60->30, silu (output stays in registers)
    run_layer<60, 30, 20, 1, false>(t1r, W3, b3, h2, 64, tba, tbb, 64, nullptr,
                                    nodes, rbj, dgj, use_lds, ls_src, ls_nw,
                                    csr_src, csr_norm, lsW, bar, lane);

    // Layer 4: K=1, 30->1, sigmoid
    float w4 = (lane < 30) ? W4[lane] : 0.f;
#pragma unroll
    for (int j = 0; j < NPW; j++) {
        float p = t1r[j] * w4;
        p += __shfl_xor(p, 1);
        p += __shfl_xor(p, 2);
        p += __shfl_xor(p, 4);
        p += __shfl_xor(p, 8);
        p += __shfl_xor(p, 16);
        p += __shfl_xor(p, 32);
        if (lane == 0) out[nodes[j]] = 1.f / (1.f + expf(-p));
    }
}

// ---------------- host ----------------
extern "C" void kernel_launch(void* const* d_in, const int* in_sizes, int n_in,
                              void* d_out, int out_size, void* d_ws, size_t ws_size,
                              hipStream_t stream) {
    const float* x  = (const float*)d_in[0];
    const int*   ei = (const int*)d_in[1];
    const float* ew = (const float*)d_in[2];
    const float* W1 = (const float*)d_in[3];
    const float* b1 = (const float*)d_in[4];
    const float* W2 = (const float*)d_in[5];
    const float* b2 = (const float*)d_in[6];
    const float* W3 = (const float*)d_in[7];
    const float* b3 = (const float*)d_in[8];
    const float* W4 = (const float*)d_in[9];
    float* out = (float*)d_out;

    const int n = N_NODES, E = N_EDGES;

    char* ws = (char*)d_ws;
    size_t off = 0;
    auto alloc = [&](size_t bytes) -> void* {
        void* p = ws + off;
        off += (bytes + 255) & ~(size_t)255;
        return p;
    };
    float* deg      = (float*)alloc(n * 4);
    int*   cnt      = (int*)alloc(n * 4);
    int*   fill     = (int*)alloc(n * 4);
    int*   rowptr   = (int*)alloc((n + 4) * 4);
    float* normw    = (float*)alloc(E * 4);
    int*   csr_src  = (int*)alloc(E * 4);
    float* csr_norm = (float*)alloc(E * 4);
    int*   bar      = (int*)alloc(128 * 4);
    float* t4a = (float*)alloc(n * 4 * 4);
    float* t4b = (float*)alloc(n * 4 * 4);
    float* tba = (float*)alloc(n * 64 * 4);
    float* tbb = (float*)alloc(n * 64 * 4);
    float* h1  = (float*)alloc(n * 64 * 4);
    float* h2  = (float*)alloc(n * 64 * 4);
    (void)ws_size; (void)n_in; (void)in_sizes; (void)out_size;

    k_init<<<(n + 255) / 256, 256, 0, stream>>>(deg, cnt, fill, bar, n);
    k_deg <<<(E + 255) / 256, 256, 0, stream>>>(ei, ew, deg, E);
    k_dis <<<(n + 255) / 256, 256, 0, stream>>>(deg, n);
    k_norm<<<(E + 255) / 256, 256, 0, stream>>>(ei, ew, deg, normw, cnt, E);
    k_scan<<<1, 1024, 0, stream>>>(cnt, rowptr, n);
    k_fill<<<(E + 255) / 256, 256, 0, stream>>>(ei, normw, rowptr, fill,
                                                csr_src, csr_norm, E);

    persistent<<<GRID, BLOCK, 0, stream>>>(
        x, rowptr, csr_src, csr_norm,
        W1, b1, W2, b2, W3, b3, W4,
        t4a, t4b, tba, tbb, h1, h2, out, bar);
}

// Round 3
// 3419.461 us; speedup vs baseline: 8.1636x; 8.1636x over previous
//
#include <hip/hip_runtime.h>
#include <math.h>

#define N_NODES 10000
#define N_EDGES 320000

// ---------------- setup kernels ----------------

__global__ void k_init(float* deg, int* cnt, int* fill, int n) {
    int i = blockIdx.x * blockDim.x + threadIdx.x;
    if (i < n) { deg[i] = 0.f; cnt[i] = 0; fill[i] = 0; }
}

__global__ void k_deg(const int* __restrict__ ei, const float* __restrict__ w,
                      float* deg, int E) {
    int e = blockIdx.x * blockDim.x + threadIdx.x;
    if (e < E) atomicAdd(&deg[ei[e]], w[e]);
}

__global__ void k_dis(float* deg, int n) {
    int i = blockIdx.x * blockDim.x + threadIdx.x;
    if (i < n) {
        float d = deg[i];
        deg[i] = (d > 0.f) ? (float)(1.0 / sqrt((double)d)) : 0.f;
    }
}

__global__ void k_norm(const int* __restrict__ ei, const float* __restrict__ w,
                       const float* __restrict__ dis, float* __restrict__ normw,
                       int* cnt, int E) {
    int e = blockIdx.x * blockDim.x + threadIdx.x;
    if (e < E) {
        int s = ei[e], d = ei[E + e];
        normw[e] = -dis[s] * w[e] * dis[d];
        atomicAdd(&cnt[d], 1);
    }
}

// single-block exclusive scan over counts -> rowptr[0..n]
__global__ void k_scan(const int* __restrict__ cnt, int* __restrict__ rowptr, int n) {
    __shared__ int part[1024];
    const int PER = 10;  // 1024*10 >= n
    int t = threadIdx.x;
    int base = t * PER;
    int local[PER];
    int s = 0;
    for (int j = 0; j < PER; j++) {
        int idx = base + j;
        int v = (idx < n) ? cnt[idx] : 0;
        local[j] = v; s += v;
    }
    part[t] = s;
    __syncthreads();
    for (int off = 1; off < 1024; off <<= 1) {
        int v = part[t];
        int u = (t >= off) ? part[t - off] : 0;
        __syncthreads();
        part[t] = v + u;
        __syncthreads();
    }
    int excl = (t > 0) ? part[t - 1] : 0;
    for (int j = 0; j < PER; j++) {
        int idx = base + j;
        if (idx < n) rowptr[idx] = excl;
        excl += local[j];
    }
    if (t == 1023) rowptr[n] = part[1023];
}

// pair CSR: {src byte-offset (stride-64 rows), norm bits}
__global__ void k_fill(const int* __restrict__ ei, const float* __restrict__ normw,
                       const int* __restrict__ rowptr, int* fill,
                       int2* __restrict__ pr, int E) {
    int e = blockIdx.x * blockDim.x + threadIdx.x;
    if (e < E) {
        int d = ei[E + e];
        int pos = atomicAdd(&fill[d], 1);
        int idx = rowptr[d] + pos;
        pr[idx] = make_int2(ei[e] << 8, __float_as_int(normw[e]));
    }
}

// ---------------- gathers ----------------
// wide: lane = channel (stride-64 float rows). Batch-8 pipelined loads.
__device__ __forceinline__ float gather_w(const char* __restrict__ tb,
                                          const int2* __restrict__ pr,
                                          int rb, int dg, int lane4) {
    float agg = 0.f;
    int e = 0;
    for (; e + 8 <= dg; e += 8) {
        int2 p[8]; float v[8];
#pragma unroll
        for (int u = 0; u < 8; u++) p[u] = pr[rb + e + u];
#pragma unroll
        for (int u = 0; u < 8; u++)
            v[u] = *(const float*)(tb + (unsigned)p[u].x + lane4);
#pragma unroll
        for (int u = 0; u < 8; u++)
            agg = fmaf(__int_as_float(p[u].y), v[u], agg);
    }
    if (e < dg) {  // masked batch-8 tail: stays pipelined
        int2 p[8]; float v[8];
#pragma unroll
        for (int u = 0; u < 8; u++) p[u] = pr[(e + u < dg) ? (rb + e + u) : rb];
#pragma unroll
        for (int u = 0; u < 8; u++)
            v[u] = *(const float*)(tb + (unsigned)p[u].x + lane4);
#pragma unroll
        for (int u = 0; u < 8; u++) {
            float w = (e + u < dg) ? __int_as_float(p[u].y) : 0.f;
            agg = fmaf(w, v[u], agg);
        }
    }
    return agg;
}

// narrow (stride-4 float rows): lane = eo*4+lc, 16 edges in parallel, batch-2.
// pair offset is src<<8; stride-4 byte offset = src<<4 = off>>4.
__device__ __forceinline__ float gather_n(const char* __restrict__ tb,
                                          const int2* __restrict__ pr,
                                          int rb, int dg, int lc4, int eo) {
    float agg = 0.f;
    int e = eo;
    for (; e + 32 <= dg; e += 32) {
        int2 p0 = pr[rb + e];
        int2 p1 = pr[rb + e + 16];
        float v0 = *(const float*)(tb + ((unsigned)p0.x >> 4) + lc4);
        float v1 = *(const float*)(tb + ((unsigned)p1.x >> 4) + lc4);
        agg = fmaf(__int_as_float(p0.y), v0, agg);
        agg = fmaf(__int_as_float(p1.y), v1, agg);
    }
    for (; e < dg; e += 16) {
        int2 p = pr[rb + e];
        agg = fmaf(__int_as_float(p.y),
                   *(const float*)(tb + ((unsigned)p.x >> 4) + lc4), agg);
    }
    agg += __shfl_xor(agg, 4);
    agg += __shfl_xor(agg, 8);
    agg += __shfl_xor(agg, 16);
    agg += __shfl_xor(agg, 32);
    return agg;  // channel lc, replicated across eo groups
}

// ---------------- dense: acc(lane=o) += sum_c t2(c) * W[c][o] ----------------
template <int CI, int CO>
__device__ __forceinline__ void dense(float& acc, float t2v,
                                      const float* __restrict__ Wk, int lane) {
#pragma unroll
    for (int c = 0; c < CI; c++) {
        float tb = __int_as_float(__builtin_amdgcn_readlane(__float_as_int(t2v), c));
        float wv;
        if (CO < 64) wv = (lane < CO) ? Wk[c * CO + lane] : 0.f;
        else         wv = Wk[c * CO + lane];
        acc = fmaf(tb, wv, acc);
    }
}

// ---------------- step kernels: one wave per node ----------------
// MODE 1: fused k0+k1  (acc = b + h@W0 + prop(h)@W1, publish T1)
// MODE 2: recurrence   (T2 = 2*prop(T1) - T0, acc += T2@Wk, publish T2)
// LAST 0: store acc + publish; 1: silu -> hout (n x 64); 2: silu + layer4 sigmoid -> out

template <int CI, int CO, int MODE, int LAST>
__global__ __launch_bounds__(256) void k_wide(
    const int* __restrict__ rowptr, const int2* __restrict__ pr,
    const float* __restrict__ hin,
    const float* __restrict__ t0, const float* __restrict__ t1,
    float* __restrict__ t2, float* __restrict__ accb,
    const float* __restrict__ Wk, const float* __restrict__ bias,
    const float* __restrict__ W4, float* __restrict__ outp)
{
    int tid = threadIdx.x;
    int lane = tid & 63;
    int node = blockIdx.x * 4 + (tid >> 6);
    int rb = rowptr[node];
    int dg = rowptr[node + 1] - rb;
    int lane4 = lane * 4;

    float acc, t2v;
    if (MODE == 1) {
        float hr = hin[node * 64 + lane];
        acc = (lane < CO) ? bias[lane] : 0.f;
        dense<CI, CO>(acc, hr, Wk, lane);
        t2v = gather_w((const char*)hin, pr, rb, dg, lane4);
        dense<CI, CO>(acc, t2v, Wk + CI * CO, lane);
    } else {
        acc = accb[node * 64 + lane];
        float t0r = t0[node * 64 + lane];
        float agg = gather_w((const char*)t1, pr, rb, dg, lane4);
        t2v = fmaf(2.f, agg, -t0r);
        dense<CI, CO>(acc, t2v, Wk, lane);
    }

    if (LAST == 0) {
        accb[node * 64 + lane] = acc;
        t2[node * 64 + lane] = t2v;
    } else if (LAST == 1) {
        outp[node * 64 + lane] = acc / (1.f + expf(-acc));  // silu; lanes>=CO: 0
    } else {
        float h = acc / (1.f + expf(-acc));
        float w4 = (lane < 30) ? W4[lane] : 0.f;
        float p = h * w4;
        p += __shfl_xor(p, 1);
        p += __shfl_xor(p, 2);
        p += __shfl_xor(p, 4);
        p += __shfl_xor(p, 8);
        p += __shfl_xor(p, 16);
        p += __shfl_xor(p, 32);
        if (lane == 0) outp[node] = 1.f / (1.f + expf(-p));
    }
}

template <int MODE, int LAST>
__global__ __launch_bounds__(256) void k_narrow(
    const int* __restrict__ rowptr, const int2* __restrict__ pr,
    const float* __restrict__ xin,
    const float* __restrict__ t0, const float* __restrict__ t1,
    float* __restrict__ t2, float* __restrict__ accb,
    const float* __restrict__ Wk, const float* __restrict__ bias,
    float* __restrict__ outp)
{
    int tid = threadIdx.x;
    int lane = tid & 63;
    int node = blockIdx.x * 4 + (tid >> 6);
    int rb = rowptr[node];
    int dg = rowptr[node + 1] - rb;
    int lc = lane & 3, eo = lane >> 2, lc4 = lc * 4;

    float acc, t2v;
    if (MODE == 1) {
        float xr = xin[node * 4 + lc];
        acc = bias[lane];
        dense<4, 64>(acc, xr, Wk, lane);
        t2v = gather_n((const char*)xin, pr, rb, dg, lc4, eo);
        dense<4, 64>(acc, t2v, Wk + 4 * 64, lane);
    } else {
        acc = accb[node * 64 + lane];
        float t0r = t0[node * 4 + lc];
        float agg = gather_n((const char*)t1, pr, rb, dg, lc4, eo);
        t2v = fmaf(2.f, agg, -t0r);
        dense<4, 64>(acc, t2v, Wk, lane);
    }

    if (LAST == 0) {
        accb[node * 64 + lane] = acc;
        if (lane < 4) t2[node * 4 + lane] = t2v;
    } else {
        outp[node * 64 + lane] = acc / (1.f + expf(-acc));
    }
}

// ---------------- host ----------------

extern "C" void kernel_launch(void* const* d_in, const int* in_sizes, int n_in,
                              void* d_out, int out_size, void* d_ws, size_t ws_size,
                              hipStream_t stream) {
    const float* x  = (const float*)d_in[0];
    const int*   ei = (const int*)d_in[1];
    const float* ew = (const float*)d_in[2];
    const float* W1 = (const float*)d_in[3];
    const float* b1 = (const float*)d_in[4];
    const float* W2 = (const float*)d_in[5];
    const float* b2 = (const float*)d_in[6];
    const float* W3 = (const float*)d_in[7];
    const float* b3 = (const float*)d_in[8];
    const float* W4 = (const float*)d_in[9];
    float* out = (float*)d_out;

    const int n = N_NODES, E = N_EDGES;

    char* ws = (char*)d_ws;
    size_t off = 0;
    auto alloc = [&](size_t bytes) -> void* {
        void* p = ws + off;
        off += (bytes + 255) & ~(size_t)255;
        return p;
    };
    float* deg    = (float*)alloc(n * 4);     // becomes dis in-place
    int*   cnt    = (int*)alloc(n * 4);
    int*   fill   = (int*)alloc(n * 4);
    int*   rowptr = (int*)alloc((n + 4) * 4);
    float* normw  = (float*)alloc((size_t)E * 4);
    int2*  pr     = (int2*)alloc((size_t)E * 8);
    float* t4a  = (float*)alloc(n * 4 * 4);
    float* t4b  = (float*)alloc(n * 4 * 4);
    float* t4c  = (float*)alloc(n * 4 * 4);
    float* tba  = (float*)alloc(n * 64 * 4);
    float* tbb  = (float*)alloc(n * 64 * 4);
    float* tbc  = (float*)alloc(n * 64 * 4);
    float* accb = (float*)alloc(n * 64 * 4);
    float* h1   = (float*)alloc(n * 64 * 4);
    float* h2   = (float*)alloc(n * 64 * 4);
    (void)ws_size; (void)n_in; (void)in_sizes; (void)out_size;

    // ---- preprocessing: degree, norm, dst-sorted pair-CSR ----
    k_init<<<(n + 255) / 256, 256, 0, stream>>>(deg, cnt, fill, n);
    k_deg <<<(E + 255) / 256, 256, 0, stream>>>(ei, ew, deg, E);
    k_dis <<<(n + 255) / 256, 256, 0, stream>>>(deg, n);
    k_norm<<<(E + 255) / 256, 256, 0, stream>>>(ei, ew, deg, normw, cnt, E);
    k_scan<<<1, 1024, 0, stream>>>(cnt, rowptr, n);
    k_fill<<<(E + 255) / 256, 256, 0, stream>>>(ei, normw, rowptr, fill, pr, E);

    const int G = n / 4;  // 2500 blocks x 256 threads, one wave per node

    // ---- Layer 1: K=120, 4 -> 64, silu -> h1 ----
    {
        const int K = 120;
        float* tb[3] = {t4a, t4b, t4c};
        k_narrow<1, 0><<<G, 256, 0, stream>>>(rowptr, pr, x, nullptr, nullptr,
                                              tb[1], accb, W1, b1, nullptr);
        for (int k = 2; k < K; k++) {
            const float* t0p = (k == 2) ? x : tb[(k - 2) % 3];
            const float* t1p = tb[(k - 1) % 3];
            const float* Wk = W1 + (size_t)k * 4 * 64;
            if (k < K - 1)
                k_narrow<2, 0><<<G, 256, 0, stream>>>(rowptr, pr, nullptr, t0p, t1p,
                                                      tb[k % 3], accb, Wk, nullptr, nullptr);
            else
                k_narrow<2, 1><<<G, 256, 0, stream>>>(rowptr, pr, nullptr, t0p, t1p,
                                                      nullptr, accb, Wk, nullptr, h1);
        }
    }

    // ---- Layer 2: K=120, 64 -> 60, silu -> h2 ----
    {
        const int K = 120;
        float* tb[3] = {tba, tbb, tbc};
        k_wide<64, 60, 1, 0><<<G, 256, 0, stream>>>(rowptr, pr, h1, nullptr, nullptr,
                                                    tb[1], accb, W2, b2, nullptr, nullptr);
        for (int k = 2; k < K; k++) {
            const float* t0p = (k == 2) ? h1 : tb[(k - 2) % 3];
            const float* t1p = tb[(k - 1) % 3];
            const float* Wk = W2 + (size_t)k * 64 * 60;
            if (k < K - 1)
                k_wide<64, 60, 2, 0><<<G, 256, 0, stream>>>(rowptr, pr, nullptr, t0p, t1p,
                                                            tb[k % 3], accb, Wk, nullptr,
                                                            nullptr, nullptr);
            else
                k_wide<64, 60, 2, 1><<<G, 256, 0, stream>>>(rowptr, pr, nullptr, t0p, t1p,
                                                            nullptr, accb, Wk, nullptr,
                                                            nullptr, h2);
        }
    }

    // ---- Layer 3 (K=20, 60 -> 30, silu) + fused Layer 4 (30 -> 1, sigmoid) ----
    {
        const int K = 20;
        float* tb[3] = {tba, tbb, tbc};
        k_wide<60, 30, 1, 0><<<G, 256, 0, stream>>>(rowptr, pr, h2, nullptr, nullptr,
                                                    tb[1], accb, W3, b3, nullptr, nullptr);
        for (int k = 2; k < K; k++) {
            const float* t0p = (k == 2) ? h2 : tb[(k - 2) % 3];
            const float* t1p = tb[(k - 1) % 3];
            const float* Wk = W3 + (size_t)k * 60 * 30;
            if (k < K - 1)
                k_wide<60, 30, 2, 0><<<G, 256, 0, stream>>>(rowptr, pr, nullptr, t0p, t1p,
                                                            tb[k % 3], accb, Wk, nullptr,
                                                            nullptr, nullptr);
            else
                k_wide<60, 30, 2, 2><<<G, 256, 0, stream>>>(rowptr, pr, nullptr, t0p, t1p,
                                                            nullptr, accb, Wk, nullptr,
                                                            W4, out);
        }
    }
}